// Round 6
// baseline (400.647 us; speedup 1.0000x reference)
//
#include <hip/hip_runtime.h>

#define NDIM 64   // D
#define FDIM 128  // 2D
#define LSTRIDE 136  // node-phase LDS row stride in halfs (128 + 8 pad)
#define YSTR 72      // edge-phase LDS row stride in halfs (64 + 8 pad -> 144 B)
#define GRID_BLOCKS 1024  // 4 blocks/CU x 256 CUs -> ALL co-resident (LDS 36.9KB<=40KB, VGPR<=128)

typedef _Float16 half8  __attribute__((ext_vector_type(8)));
typedef _Float16 half4v __attribute__((ext_vector_type(4)));
typedef float    float4v __attribute__((ext_vector_type(4)));

// ---------------------------------------------------------------------------
// Fused kernel v2: node GEMM phase -> grid barrier -> edge combine phase.
// R2's fusion failed at 2 blocks/CU (8 waves/CU, occupancy cliff on the
// gather). This version holds the split kernels' 16 waves/CU: LDS 36.9 KB
// -> 4 blocks/CU, grid 1024 = 4x256 -> all blocks resident -> the
// arrive-and-spin barrier cannot deadlock. Coherence identical to R2
// (which passed): release = syncthreads + threadfence + agent-scope
// fetch_add; acquire = agent-scope spin load + syncthreads + threadfence.
// NOTE: no __syncthreads inside either phase loop (edge trip counts are
// wave-divergent; node loop is block-uniform but also barrier-free).
// ---------------------------------------------------------------------------
__global__ __launch_bounds__(256, 4) void fused_edge_mlp_kernel(
    const float* __restrict__ x,        // [N][64]
    const float* __restrict__ W1,       // [64][128]
    const float* __restrict__ b1,       // [64]
    const int*   __restrict__ ei,       // [2E]
    const float* __restrict__ W2,       // [64]
    const float* __restrict__ b2,       // [1]
    _Float16*    __restrict__ Yab,      // [N][128] workspace table
    float*       __restrict__ out,      // [E]
    unsigned int* flag,                 // ws barrier counter (memset to 0)
    int N, int E)
{
    __shared__ _Float16 lds[4][64 * YSTR];  // 36.9 KB; node phase uses first 2176 halfs/wave

    const int wave = threadIdx.x >> 6;
    const int lane = threadIdx.x & 63;
    const int c  = lane & 15;   // MFMA: j-in-tile / edge-in-tile
    const int g  = lane >> 4;   // MFMA: k-group / C row-group
    const int r8 = lane >> 3;   // gather: row-in-group 0..7
    const int h  = lane & 7;    // gather: 16-B chunk 0..7 within 128-B row

    // ================= phase 1: node half-layers via MFMA =================
    //   Yab[n][j]    = b1[j] + sum_k x[n][k] * W1[j][k]        (j < 64)
    //   Yab[n][64+j] =         sum_k x[n][k] * W1[j][64+k]
    const int NU = (N + 127) >> 7;   // units of 128 nodes (4 waves x 32)
    for (int u = blockIdx.x; u < NU; u += gridDim.x) {
        const int node0 = (u * 4 + wave) * 32;
        if (node0 >= N) continue;    // wave-uniform; N % 32 == 0

        half8 Bf[2][2];   // [tile][kk]
        #pragma unroll
        for (int t2 = 0; t2 < 2; t2++) {
            #pragma unroll
            for (int kk = 0; kk < 2; kk++) {
                const float* bp = x + (size_t)(node0 + t2 * 16 + c) * NDIM
                                  + kk * 32 + g * 8;
                float4v b0 = __builtin_nontemporal_load((const float4v*)bp);
                float4v b1v_ = __builtin_nontemporal_load((const float4v*)(bp + 4));
                half8 B;
                B[0] = (_Float16)b0[0]; B[1] = (_Float16)b0[1];
                B[2] = (_Float16)b0[2]; B[3] = (_Float16)b0[3];
                B[4] = (_Float16)b1v_[0]; B[5] = (_Float16)b1v_[1];
                B[6] = (_Float16)b1v_[2]; B[7] = (_Float16)b1v_[3];
                Bf[t2][kk] = B;
            }
        }

        float4v C[2][8];
        #pragma unroll
        for (int t2 = 0; t2 < 2; t2++)
            #pragma unroll
            for (int mt = 0; mt < 8; mt++)
                C[t2][mt] = (float4v){0.f, 0.f, 0.f, 0.f};

        #pragma unroll
        for (int kk = 0; kk < 2; kk++) {
            #pragma unroll
            for (int mt = 0; mt < 8; mt++) {
                // A-fragment straight from W1 (f32, 32 KB, cache-hot).
                const float* wp = (mt < 4)
                    ? (W1 + (size_t)(mt * 16 + c) * FDIM + kk * 32 + g * 8)
                    : (W1 + (size_t)((mt - 4) * 16 + c) * FDIM + NDIM + kk * 32 + g * 8);
                float4v a0 = *(const float4v*)wp;
                float4v a1 = *(const float4v*)(wp + 4);
                half8 Af;
                Af[0] = (_Float16)a0[0]; Af[1] = (_Float16)a0[1];
                Af[2] = (_Float16)a0[2]; Af[3] = (_Float16)a0[3];
                Af[4] = (_Float16)a1[0]; Af[5] = (_Float16)a1[1];
                Af[6] = (_Float16)a1[2]; Af[7] = (_Float16)a1[3];
                C[0][mt] = __builtin_amdgcn_mfma_f32_16x16x32_f16(Af, Bf[0][kk], C[0][mt], 0, 0, 0);
                C[1][mt] = __builtin_amdgcn_mfma_f32_16x16x32_f16(Af, Bf[1][kk], C[1][mt], 0, 0, 0);
            }
        }

        // Epilogue: +b1 (j<64), cvt f16, LDS transpose, coalesced stores.
        #pragma unroll
        for (int t2 = 0; t2 < 2; t2++) {
            #pragma unroll
            for (int mt = 0; mt < 8; mt++) {
                float4v badd = (float4v){0.f, 0.f, 0.f, 0.f};
                if (mt < 4) badd = *(const float4v*)(b1 + mt * 16 + g * 4);
                half4v o;
                #pragma unroll
                for (int r = 0; r < 4; r++) o[r] = (_Float16)(C[t2][mt][r] + badd[r]);
                *(half4v*)&lds[wave][c * LSTRIDE + mt * 16 + g * 4] = o;
            }
            #pragma unroll
            for (int p = 0; p < 4; p++) {
                const int node  = 4 * p + (lane >> 4);
                const int chunk = lane & 15;
                half8 v = *(const half8*)&lds[wave][node * LSTRIDE + chunk * 8];
                *(half8*)(Yab + (size_t)(node0 + t2 * 16 + node) * FDIM + chunk * 8) = v;
            }
        }
    }

    // layer-2 constants: independent of Yab -> load before the barrier
    half8 Bw[2];
    #pragma unroll
    for (int kk = 0; kk < 2; kk++) {
        const float* wp = W2 + kk * 32 + g * 8;
        float4v w0 = *(const float4v*)wp;
        float4v w1 = *(const float4v*)(wp + 4);
        half8 B;
        B[0] = (_Float16)w0[0]; B[1] = (_Float16)w0[1];
        B[2] = (_Float16)w0[2]; B[3] = (_Float16)w0[3];
        B[4] = (_Float16)w1[0]; B[5] = (_Float16)w1[1];
        B[6] = (_Float16)w1[2]; B[7] = (_Float16)w1[3];
        Bw[kk] = B;
    }
    const float b2v = b2[0];
    const half8 zero8 = (half8)(_Float16)0.0f;

    // ========================= grid barrier ==============================
    __syncthreads();     // all waves' Yab stores issued & drained (vmcnt)
    __threadfence();     // release: write back dirty XCD L2
    if (threadIdx.x == 0) {
        __hip_atomic_fetch_add(flag, 1u, __ATOMIC_ACQ_REL, __HIP_MEMORY_SCOPE_AGENT);
        while (__hip_atomic_load(flag, __ATOMIC_ACQUIRE, __HIP_MEMORY_SCOPE_AGENT)
               < (unsigned)gridDim.x) {
            __builtin_amdgcn_s_sleep(2);
        }
    }
    __syncthreads();
    __threadfence();     // acquire: invalidate L1 / XCD L2 before gather

    // ================= phase 2: per-edge combine, MFMA layer-2 ============
    //   out[e] = b2 + sum_j W2[j] * relu(Yab[s][j] + Yab[d][64+j])
    // R4 gather shape: 8 rows x 8 lanes x 16 B = one full 128-B line per
    // endpoint (1 request). Wave-private LDS remap to MFMA (c,g) layout.
    const long ntiles  = (long)E >> 5;        // 32 edges per tile
    const long tstride = (long)gridDim.x * 4;
    for (long t = (long)blockIdx.x * 4 + wave; t < ntiles; t += tstride) {
        const long e0 = t * 32;

        int se[4], de[4];
        #pragma unroll
        for (int j = 0; j < 4; j++) {
            se[j] = __builtin_nontemporal_load(ei + e0 + 8 * j + r8);
            de[j] = __builtin_nontemporal_load(ei + (size_t)E + e0 + 8 * j + r8);
        }

        half8 sv[4], dv[4];
        #pragma unroll
        for (int j = 0; j < 4; j++) {
            sv[j] = *(const half8*)(Yab + (size_t)se[j] * FDIM + h * 8);
            dv[j] = *(const half8*)(Yab + (size_t)de[j] * FDIM + NDIM + h * 8);
        }

        #pragma unroll
        for (int j = 0; j < 4; j++) {
            *(half8*)&lds[wave][(8 * j + r8) * YSTR + h * 8] = sv[j];
            *(half8*)&lds[wave][(32 + 8 * j + r8) * YSTR + h * 8] = dv[j];
        }

        #pragma unroll
        for (int tt = 0; tt < 2; tt++) {
            float4v C = (float4v){0.f, 0.f, 0.f, 0.f};
            #pragma unroll
            for (int kk = 0; kk < 2; kk++) {
                half8 A  = *(const half8*)&lds[wave][(tt * 16 + c) * YSTR + kk * 32 + g * 8];
                half8 Bv = *(const half8*)&lds[wave][(32 + tt * 16 + c) * YSTR + kk * 32 + g * 8];
                half8 H = A + Bv;                         // v_pk_add_f16
                H = __builtin_elementwise_max(H, zero8);  // v_pk_max_f16 (relu)
                C = __builtin_amdgcn_mfma_f32_16x16x32_f16(H, Bw[kk], C, 0, 0, 0);
            }
            if (c == 0) {
                float4v o;
                #pragma unroll
                for (int r = 0; r < 4; r++) o[r] = C[r] + b2v;
                __builtin_nontemporal_store(o, (float4v*)(out + e0 + tt * 16 + g * 4));
            }
        }
    }
}

// ---------------- fp32 fallback (ws too small; not expected) -----------------
__global__ __launch_bounds__(256) void edge_mlp_fp32_kernel(
    const float* __restrict__ x, const int* __restrict__ ei,
    const float* __restrict__ W1, const float* __restrict__ b1,
    const float* __restrict__ W2, const float* __restrict__ b2,
    float* __restrict__ out, int E)
{
    int e = blockIdx.x * blockDim.x + threadIdx.x;
    if (e >= E) return;
    int s = ei[e];
    int d = ei[E + e];
    const float* xs = x + (size_t)s * NDIM;
    const float* xd = x + (size_t)d * NDIM;
    float acc = b2[0];
    for (int j = 0; j < NDIM; j++) {
        float h = b1[j];
        for (int k = 0; k < NDIM; k++) {
            h += xs[k] * W1[j * FDIM + k] + xd[k] * W1[j * FDIM + 64 + k];
        }
        acc += W2[j] * (h > 0.f ? h : 0.f);
    }
    out[e] = acc;
}

extern "C" void kernel_launch(void* const* d_in, const int* in_sizes, int n_in,
                              void* d_out, int out_size, void* d_ws, size_t ws_size,
                              hipStream_t stream) {
    const float* x  = (const float*)d_in[0];
    const int*   ei = (const int*)d_in[1];
    const float* W1 = (const float*)d_in[2];
    const float* b1 = (const float*)d_in[3];
    const float* W2 = (const float*)d_in[4];
    const float* b2 = (const float*)d_in[5];
    float* out = (float*)d_out;
    const int E = out_size;
    const int N = in_sizes[0] / NDIM;

    const size_t tbl_off   = 256;  // flag at ws[0], Yab after (aligned)
    const size_t tbl_bytes = (size_t)N * FDIM * sizeof(_Float16);   // 25.6 MB

    if (ws_size >= tbl_off + tbl_bytes && (N % 32) == 0 && (E % 64) == 0) {
        unsigned int* flag = (unsigned int*)d_ws;
        _Float16* Yab = (_Float16*)((char*)d_ws + tbl_off);

        hipMemsetAsync(d_ws, 0, sizeof(unsigned int), stream);  // flag = 0
        fused_edge_mlp_kernel<<<GRID_BLOCKS, 256, 0, stream>>>(
            x, W1, b1, ei, W2, b2, Yab, out, flag, N, E);
    } else {
        edge_mlp_fp32_kernel<<<(E + 255) / 256, 256, 0, stream>>>(
            x, ei, W1, b1, W2, b2, out, E);
    }
}

// Round 7
// 133.735 us; speedup vs baseline: 2.9958x; 2.9958x over previous
//
#include <hip/hip_runtime.h>

#define NDIM 64   // D
#define FDIM 128  // 2D
#define LSTRIDE 136  // node-kernel LDS row stride in halfs (128 + 8 pad)
#define YSTR 72      // edge-kernel LDS row stride in halfs (64 + 8 pad -> 144 B)

typedef _Float16 half8  __attribute__((ext_vector_type(8)));
typedef _Float16 half4v __attribute__((ext_vector_type(4)));
typedef float    float4v __attribute__((ext_vector_type(4)));

// ---------------------------------------------------------------------------
// Kernel 1: node half-layers via MFMA; 32 nodes/wave. W1 A-fragments loaded
// directly (f32, 32 KB, cache-hot) with inline f16 conversion.
//   Yab[n][j]    = b1[j] + sum_k x[n][k] * W1[j][k]        (j < 64)
//   Yab[n][64+j] =         sum_k x[n][k] * W1[j][64+k]
// ---------------------------------------------------------------------------
__global__ __launch_bounds__(256) void node_gemm_kernel(
    const float* __restrict__ x,        // [N][64]
    const float* __restrict__ W1,       // [64][128]
    const float* __restrict__ b1,       // [64]
    _Float16* __restrict__ Yab,         // [N][128]
    int N)
{
    __shared__ _Float16 lds[4][16 * LSTRIDE];   // per-wave transpose slice

    const int wave = threadIdx.x >> 6;
    const int lane = threadIdx.x & 63;
    const int c = lane & 15;   // A: j-in-tile | B/C: node-in-tile
    const int g = lane >> 4;   // k-group / C row-group

    const int node0 = (blockIdx.x * 4 + wave) * 32;   // 32 nodes per wave
    if (node0 >= N) return;    // wave-uniform; no barriers in this kernel

    half8 Bf[2][2];   // [tile][kk]
    #pragma unroll
    for (int t2 = 0; t2 < 2; t2++) {
        #pragma unroll
        for (int kk = 0; kk < 2; kk++) {
            const float* bp = x + (size_t)(node0 + t2 * 16 + c) * NDIM
                              + kk * 32 + g * 8;
            float4v b0 = __builtin_nontemporal_load((const float4v*)bp);
            float4v b1v_ = __builtin_nontemporal_load((const float4v*)(bp + 4));
            half8 B;
            B[0] = (_Float16)b0[0]; B[1] = (_Float16)b0[1];
            B[2] = (_Float16)b0[2]; B[3] = (_Float16)b0[3];
            B[4] = (_Float16)b1v_[0]; B[5] = (_Float16)b1v_[1];
            B[6] = (_Float16)b1v_[2]; B[7] = (_Float16)b1v_[3];
            Bf[t2][kk] = B;
        }
    }

    float4v C[2][8];
    #pragma unroll
    for (int t2 = 0; t2 < 2; t2++)
        #pragma unroll
        for (int mt = 0; mt < 8; mt++)
            C[t2][mt] = (float4v){0.f, 0.f, 0.f, 0.f};

    #pragma unroll
    for (int kk = 0; kk < 2; kk++) {
        #pragma unroll
        for (int mt = 0; mt < 8; mt++) {
            const float* wp = (mt < 4)
                ? (W1 + (size_t)(mt * 16 + c) * FDIM + kk * 32 + g * 8)
                : (W1 + (size_t)((mt - 4) * 16 + c) * FDIM + NDIM + kk * 32 + g * 8);
            float4v a0 = *(const float4v*)wp;
            float4v a1 = *(const float4v*)(wp + 4);
            half8 Af;
            Af[0] = (_Float16)a0[0]; Af[1] = (_Float16)a0[1];
            Af[2] = (_Float16)a0[2]; Af[3] = (_Float16)a0[3];
            Af[4] = (_Float16)a1[0]; Af[5] = (_Float16)a1[1];
            Af[6] = (_Float16)a1[2]; Af[7] = (_Float16)a1[3];
            C[0][mt] = __builtin_amdgcn_mfma_f32_16x16x32_f16(Af, Bf[0][kk], C[0][mt], 0, 0, 0);
            C[1][mt] = __builtin_amdgcn_mfma_f32_16x16x32_f16(Af, Bf[1][kk], C[1][mt], 0, 0, 0);
        }
    }

    #pragma unroll
    for (int t2 = 0; t2 < 2; t2++) {
        #pragma unroll
        for (int mt = 0; mt < 8; mt++) {
            float4v badd = (float4v){0.f, 0.f, 0.f, 0.f};
            if (mt < 4) badd = *(const float4v*)(b1 + mt * 16 + g * 4);
            half4v o;
            #pragma unroll
            for (int r = 0; r < 4; r++) o[r] = (_Float16)(C[t2][mt][r] + badd[r]);
            *(half4v*)&lds[wave][c * LSTRIDE + mt * 16 + g * 4] = o;
        }
        #pragma unroll
        for (int p = 0; p < 4; p++) {
            const int node  = 4 * p + (lane >> 4);
            const int chunk = lane & 15;
            half8 v = *(const half8*)&lds[wave][node * LSTRIDE + chunk * 8];
            *(half8*)(Yab + (size_t)(node0 + t2 * 16 + node) * FDIM + chunk * 8) = v;
        }
    }
}

// ---------------------------------------------------------------------------
// Kernel 2 (R4-best): per-edge combine, full-line gathers + LDS fragment
// remap. Each gather instruction covers 8 rows x 128 B with 8 contiguous
// 16-B lanes per row -> ONE line request per endpoint (2e6 total).
// Gathered lines land in a wave-private LDS slice (in-order DS, no barrier);
// MFMA fragments are re-read in (c,g) layout. +8-half row pad keeps read
// aliasing at the free 2-way level.
//   out[e] = b2 + sum_j W2[j] * relu(Yab[s][j] + Yab[d][64+j])
// ---------------------------------------------------------------------------
__global__ __launch_bounds__(256) void edge_combine_kernel(
    const _Float16* __restrict__ Yab,  // [N][128]
    const int* __restrict__ ei,        // [2E]
    const float* __restrict__ W2,      // [64]
    const float* __restrict__ b2,      // [1]
    float* __restrict__ out,           // [E]
    int E)
{
    __shared__ _Float16 lds[4][64 * YSTR];  // 64 rows/wave (32 src + 32 dst), 36.9 KB/block

    const int lane = threadIdx.x & 63;
    const int wave = threadIdx.x >> 6;
    const int c  = lane & 15;   // MFMA: edge-in-tile (A row)
    const int g  = lane >> 4;   // MFMA: k-group
    const int r8 = lane >> 3;   // gather: row-in-group 0..7
    const int h  = lane & 7;    // gather: 16-B chunk 0..7 within 128-B row

    const long e0 = (long)(blockIdx.x * 4 + wave) * 32;  // 32 edges per wave
    if (e0 >= E) return;        // wave-uniform (E % 32 == 0)

    half8 Bw[2];
    #pragma unroll
    for (int kk = 0; kk < 2; kk++) {
        const float* wp = W2 + kk * 32 + g * 8;
        float4v w0 = *(const float4v*)wp;
        float4v w1 = *(const float4v*)(wp + 4);
        half8 B;
        B[0] = (_Float16)w0[0]; B[1] = (_Float16)w0[1];
        B[2] = (_Float16)w0[2]; B[3] = (_Float16)w0[3];
        B[4] = (_Float16)w1[0]; B[5] = (_Float16)w1[1];
        B[6] = (_Float16)w1[2]; B[7] = (_Float16)w1[3];
        Bw[kk] = B;
    }
    const float b2v = b2[0];

    // indices: instruction j covers edges e0+8j .. e0+8j+7; 8-way lane bcast
    int se[4], de[4];
    #pragma unroll
    for (int j = 0; j < 4; j++)
        se[j] = __builtin_nontemporal_load(ei + e0 + 8 * j + r8);
    #pragma unroll
    for (int j = 0; j < 4; j++)
        de[j] = __builtin_nontemporal_load(ei + (size_t)E + e0 + 8 * j + r8);

    // full-line gathers: 8 lanes x 16 B contiguous per row = 1 request/endpoint
    half8 sv[4], dv[4];
    #pragma unroll
    for (int j = 0; j < 4; j++)
        sv[j] = *(const half8*)(Yab + (size_t)se[j] * FDIM + h * 8);        // halfs [0,64)
    #pragma unroll
    for (int j = 0; j < 4; j++)
        dv[j] = *(const half8*)(Yab + (size_t)de[j] * FDIM + NDIM + h * 8); // halfs [64,128)

    // stage into wave-private LDS (rows 0..31 = src, 32..63 = dst)
    #pragma unroll
    for (int j = 0; j < 4; j++)
        *(half8*)&lds[wave][(8 * j + r8) * YSTR + h * 8] = sv[j];
    #pragma unroll
    for (int j = 0; j < 4; j++)
        *(half8*)&lds[wave][(32 + 8 * j + r8) * YSTR + h * 8] = dv[j];

    // MFMA fragments re-read in (c,g) layout; arithmetic identical to before
    const half8 zero8 = (half8)(_Float16)0.0f;
    #pragma unroll
    for (int t = 0; t < 2; t++) {
        float4v C = (float4v){0.f, 0.f, 0.f, 0.f};
        #pragma unroll
        for (int kk = 0; kk < 2; kk++) {
            half8 A  = *(const half8*)&lds[wave][(t * 16 + c) * YSTR + kk * 32 + g * 8];
            half8 Bv = *(const half8*)&lds[wave][(32 + t * 16 + c) * YSTR + kk * 32 + g * 8];
            half8 H = A + Bv;                         // v_pk_add_f16
            H = __builtin_elementwise_max(H, zero8);  // v_pk_max_f16 (relu)
            C = __builtin_amdgcn_mfma_f32_16x16x32_f16(H, Bw[kk], C, 0, 0, 0);
        }
        if (c == 0) {
            float4v o;
            #pragma unroll
            for (int r = 0; r < 4; r++) o[r] = C[r] + b2v;
            __builtin_nontemporal_store(o, (float4v*)(out + e0 + t * 16 + g * 4));
        }
    }
}

// ---------------- fp32 fallback (ws too small; not expected) -----------------
__global__ __launch_bounds__(256) void edge_mlp_fp32_kernel(
    const float* __restrict__ x, const int* __restrict__ ei,
    const float* __restrict__ W1, const float* __restrict__ b1,
    const float* __restrict__ W2, const float* __restrict__ b2,
    float* __restrict__ out, int E)
{
    int e = blockIdx.x * blockDim.x + threadIdx.x;
    if (e >= E) return;
    int s = ei[e];
    int d = ei[E + e];
    const float* xs = x + (size_t)s * NDIM;
    const float* xd = x + (size_t)d * NDIM;
    float acc = b2[0];
    for (int j = 0; j < NDIM; j++) {
        float h = b1[j];
        for (int k = 0; k < NDIM; k++) {
            h += xs[k] * W1[j * FDIM + k] + xd[k] * W1[j * FDIM + 64 + k];
        }
        acc += W2[j] * (h > 0.f ? h : 0.f);
    }
    out[e] = acc;
}

extern "C" void kernel_launch(void* const* d_in, const int* in_sizes, int n_in,
                              void* d_out, int out_size, void* d_ws, size_t ws_size,
                              hipStream_t stream) {
    const float* x  = (const float*)d_in[0];
    const int*   ei = (const int*)d_in[1];
    const float* W1 = (const float*)d_in[2];
    const float* b1 = (const float*)d_in[3];
    const float* W2 = (const float*)d_in[4];
    const float* b2 = (const float*)d_in[5];
    float* out = (float*)d_out;
    const int E = out_size;
    const int N = in_sizes[0] / NDIM;

    const size_t tbl_bytes = (size_t)N * FDIM * sizeof(_Float16);   // 25.6 MB

    if (ws_size >= tbl_bytes && (N % 32) == 0 && (E % 64) == 0) {
        _Float16* Yab = (_Float16*)d_ws;

        const int nblocks = (N + 127) / 128;   // 4 waves x 32 nodes per block
        node_gemm_kernel<<<nblocks, 256, 0, stream>>>(x, W1, b1, Yab, N);

        const int eblocks = (E + 127) / 128;   // 4 waves x 32 edges per block
        edge_combine_kernel<<<eblocks, 256, 0, stream>>>(
            Yab, ei, W2, b2, out, E);
    } else {
        edge_mlp_fp32_kernel<<<(E + 255) / 256, 256, 0, stream>>>(
            x, ei, W1, b1, W2, b2, out, E);
    }
}